// Round 6
// baseline (208.061 us; speedup 1.0000x reference)
//
#include <hip/hip_runtime.h>

#define N_NODES 50000
#define E_EDGES 800000
#define DIN 128
#define DOUT 64
#define NBUK 196            // bucket = row >> 8; 196*256 = 50176 >= N
#define BUKCAP 4608         // fixed bucket capacity (mean 4092, +8 sigma)
#define ASTRIDE 136         // bf16 LDS row stride

typedef short short8 __attribute__((ext_vector_type(8)));
typedef float f32x4 __attribute__((ext_vector_type(4)));

static __device__ __forceinline__ short f2bf(float f)
{
    union { float f; unsigned u; } x{f};
    const unsigned r = x.u + 0x7FFFu + ((x.u >> 16) & 1u);   // RNE
    return (short)(r >> 16);
}

// ---------------- K0: one-time prep — W^T bf16, BN scale/shift --------------
__global__ void k_prep(const float* __restrict__ W, const float* __restrict__ gamma,
                       const float* __restrict__ beta, const float* __restrict__ mean,
                       const float* __restrict__ var,
                       unsigned short* __restrict__ Wt, float* __restrict__ sc,
                       float* __restrict__ sh)
{
    const int idx = blockIdx.x * 256 + threadIdx.x;      // 8192 threads
    const int n = idx >> 7, k = idx & 127;
    Wt[n * DIN + k] = (unsigned short)f2bf(W[k * DOUT + n]);
    if (idx < DIN) {
        const float s = gamma[idx] / sqrtf(var[idx] + 1e-5f);
        sc[idx] = s;
        sh[idx] = beta[idx] - mean[idx] * s;
    }
}

// ---------------- K1: fused L2norm + BN + Linear via bf16 MFMA --------------
__global__ __launch_bounds__(256) void k_x(
    const float* __restrict__ H, const float* __restrict__ sc,
    const float* __restrict__ sh, const unsigned short* __restrict__ Wt,
    const float* __restrict__ bias, float* __restrict__ X)
{
    __shared__ short A_s[64][ASTRIDE];
    __shared__ short B_s[64][ASTRIDE];
    const int t = threadIdx.x;
    const int l = t & 63, wv = t >> 6;
    const int R0 = blockIdx.x * 64;

    {   // stage A: 4 threads per row
        const int rloc = t >> 2, sub = t & 3;
        const int r = R0 + rloc;
        float4 h[8];
        if (r < N_NODES) {
            const float4* hp = (const float4*)(H + (size_t)r * DIN + sub * 32);
#pragma unroll
            for (int i = 0; i < 8; ++i) h[i] = hp[i];
        } else {
#pragma unroll
            for (int i = 0; i < 8; ++i) h[i] = make_float4(0.f, 0.f, 0.f, 0.f);
        }
        float ss = 0.f;
#pragma unroll
        for (int i = 0; i < 8; ++i)
            ss += h[i].x * h[i].x + h[i].y * h[i].y + h[i].z * h[i].z + h[i].w * h[i].w;
        ss += __shfl_xor(ss, 1, 64);
        ss += __shfl_xor(ss, 2, 64);
        const float inv = 1.0f / fmaxf(sqrtf(ss), 1e-12f);

        const float4* scp = (const float4*)(sc + sub * 32);
        const float4* shp = (const float4*)(sh + sub * 32);
#pragma unroll
        for (int i = 0; i < 8; ++i) {
            const float4 s4 = scp[i], b4 = shp[i];
            const float e0 = h[i].x * inv * s4.x + b4.x;
            const float e1 = h[i].y * inv * s4.y + b4.y;
            const float e2 = h[i].z * inv * s4.z + b4.z;
            const float e3 = h[i].w * inv * s4.w + b4.w;
            const unsigned u0 = (unsigned short)f2bf(e0) | ((unsigned)(unsigned short)f2bf(e1) << 16);
            const unsigned u1 = (unsigned short)f2bf(e2) | ((unsigned)(unsigned short)f2bf(e3) << 16);
            *(uint2*)&A_s[rloc][sub * 32 + i * 4] = make_uint2(u0, u1);
        }
    }
    {   // stage B: W^T bf16 -> LDS
        const int n = t >> 2, koff = (t & 3) * 32;
        const uint4* src = (const uint4*)(Wt + n * DIN + koff);
#pragma unroll
        for (int i = 0; i < 4; ++i)
            *(uint4*)&B_s[n][koff + i * 8] = src[i];
    }
    __syncthreads();

    const int ml = l & 15, q = l >> 4;
    f32x4 c0, c1, c2, c3;
    {
        const float b0 = bias[ml],      b1 = bias[16 + ml];
        const float b2 = bias[32 + ml], b3 = bias[48 + ml];
        c0 = f32x4{b0, b0, b0, b0};
        c1 = f32x4{b1, b1, b1, b1};
        c2 = f32x4{b2, b2, b2, b2};
        c3 = f32x4{b3, b3, b3, b3};
    }
#pragma unroll
    for (int k0 = 0; k0 < 4; ++k0) {
        const short8 a  = *(const short8*)&A_s[wv * 16 + ml][k0 * 32 + q * 8];
        const short8 b0 = *(const short8*)&B_s[ml][k0 * 32 + q * 8];
        const short8 b1 = *(const short8*)&B_s[16 + ml][k0 * 32 + q * 8];
        const short8 b2 = *(const short8*)&B_s[32 + ml][k0 * 32 + q * 8];
        const short8 b3 = *(const short8*)&B_s[48 + ml][k0 * 32 + q * 8];
        c0 = __builtin_amdgcn_mfma_f32_16x16x32_bf16(a, b0, c0, 0, 0, 0);
        c1 = __builtin_amdgcn_mfma_f32_16x16x32_bf16(a, b1, c1, 0, 0, 0);
        c2 = __builtin_amdgcn_mfma_f32_16x16x32_bf16(a, b2, c2, 0, 0, 0);
        c3 = __builtin_amdgcn_mfma_f32_16x16x32_bf16(a, b3, c3, 0, 0, 0);
    }
#pragma unroll
    for (int i = 0; i < 4; ++i) {
        const int row = R0 + wv * 16 + q * 4 + i;
        if (row < N_NODES) {
            float* xr = X + (size_t)row * DOUT;
            xr[ml]      = c0[i];
            xr[16 + ml] = c1[i];
            xr[32 + ml] = c2[i];
            xr[48 + ml] = c3[i];
        }
    }
}

// ---------------- K2: pass A — bucket sort (fixed-cap) + per-row count ------
// pack: col(16b) | (row&255)<<16 | (row>>8)<<24
__global__ __launch_bounds__(256) void k_passA(
    const int* __restrict__ rows, const int* __restrict__ cols,
    const float* __restrict__ vals, int* __restrict__ cnt,
    int* __restrict__ gcursor, uint2* __restrict__ mid)
{
    __shared__ int lhist[NBUK], lstart[NBUK], lcur[NBUK], gbase[NBUK];
    __shared__ int scn[256];
    __shared__ uint2 lbin[1024];
    const int t = threadIdx.x;
    const int e0 = blockIdx.x * 1024;
    const int nC = min(1024, E_EDGES - e0);

    if (t < NBUK) lhist[t] = 0;
    __syncthreads();

    uint2 pr[4];
#pragma unroll
    for (int k = 0; k < 4; ++k) {
        const int e = e0 + k * 256 + t;
        if (e < E_EDGES) {
            const int r = rows[e];
            pr[k] = make_uint2(__float_as_uint(vals[e]),
                               (unsigned)cols[e] | ((unsigned)(r & 255) << 16)
                                                 | ((unsigned)(r >> 8) << 24));
            atomicAdd(&lhist[r >> 8], 1);
            atomicAdd(&cnt[r], 1);            // fused exact per-row count
        } else {
            pr[k] = make_uint2(0u, 0xFFFFFFFFu);
        }
    }
    __syncthreads();

    const int v = (t < NBUK) ? lhist[t] : 0;
    scn[t] = v;
    __syncthreads();
    for (int o = 1; o < 256; o <<= 1) {
        const int u = (t >= o) ? scn[t - o] : 0;
        __syncthreads();
        scn[t] += u;
        __syncthreads();
    }
    if (t < NBUK) {
        const int ex = scn[t] - v;
        lstart[t] = ex;
        lcur[t] = ex;
        gbase[t] = t * BUKCAP + (v ? atomicAdd(&gcursor[t], v) : 0);
    }
    __syncthreads();

#pragma unroll
    for (int k = 0; k < 4; ++k) {
        const unsigned pk = pr[k].y;
        if (pk != 0xFFFFFFFFu) {
            const int bk = pk >> 24;
            lbin[atomicAdd(&lcur[bk], 1)] = pr[k];
        }
    }
    __syncthreads();

    for (int i = t; i < nC; i += 256) {
        const uint2 p = lbin[i];
        const int bk = p.y >> 24;
        mid[gbase[bk] + (i - lstart[bk])] = p;
    }
}

// ---------------- K3a: block-local exclusive row scan (49 blocks) -----------
__global__ __launch_bounds__(256) void k_rscan1(
    const int* __restrict__ cnt, int* __restrict__ startL,
    int* __restrict__ cursorL, int* __restrict__ bsum)
{
    const int b = blockIdx.x, t = threadIdx.x;
    const int base = b * 1024 + t * 4;
    int c0 = 0, c1 = 0, c2 = 0, c3 = 0;
    if (base + 3 < N_NODES) {
        const int4 c = *(const int4*)(cnt + base);
        c0 = c.x; c1 = c.y; c2 = c.z; c3 = c.w;
    } else {
        if (base     < N_NODES) c0 = cnt[base];
        if (base + 1 < N_NODES) c1 = cnt[base + 1];
        if (base + 2 < N_NODES) c2 = cnt[base + 2];
        if (base + 3 < N_NODES) c3 = cnt[base + 3];
    }
    const int s = c0 + c1 + c2 + c3;
    const int lane = t & 63, wv = t >> 6;
    int x = s;
#pragma unroll
    for (int o = 1; o < 64; o <<= 1) {
        const int y = __shfl_up(x, o, 64);
        if (lane >= o) x += y;
    }
    __shared__ int wsum[4];
    if (lane == 63) wsum[wv] = x;
    __syncthreads();
    int wpre = 0;
    for (int i = 0; i < wv; ++i) wpre += wsum[i];
    const int ex = wpre + x - s;
    const int p0 = ex, p1 = ex + c0, p2 = p1 + c1, p3 = p2 + c2;
    if (base + 3 < N_NODES) {
        *(int4*)(startL + base)  = make_int4(p0, p1, p2, p3);
        *(int4*)(cursorL + base) = make_int4(p0, p1, p2, p3);
    } else {
        const int pv[4] = {p0, p1, p2, p3};
        for (int i = 0; i < 4; ++i) {
            if (base + i <= N_NODES) startL[base + i] = pv[i];
            if (base + i <  N_NODES) cursorL[base + i] = pv[i];
        }
    }
    if (t == 255) bsum[b] = ex + s;
}

// ---------------- K3b: scan 49 block sums (1 wave) --------------------------
__global__ void k_rscan2(const int* __restrict__ bsum, int* __restrict__ boff)
{
    const int lane = threadIdx.x;
    const int v = (lane < 49) ? bsum[lane] : 0;
    int x = v;
#pragma unroll
    for (int o = 1; o < 64; o <<= 1) {
        const int y = __shfl_up(x, o, 64);
        if (lane >= o) x += y;
    }
    if (lane < 49) boff[lane] = x - v;
}

// ---------------- K4: scatter bucket-sorted mid -> exact CSR ev -------------
// 5 slices per bucket; writes land inside the bucket's ~32KB window.
__global__ __launch_bounds__(256) void k_scatter2(
    const int* __restrict__ gcursor, const uint2* __restrict__ mid,
    int* __restrict__ cursorL, const int* __restrict__ boff,
    uint2* __restrict__ ev)
{
    const int b  = blockIdx.x / 5;
    const int sl = blockIdx.x % 5;
    const int cntb = gcursor[b];
    const int i0 = sl * 1024;
    if (i0 >= cntb) return;
    const int i1 = min(i0 + 1024, cntb);
    const uint2* src = mid + (size_t)b * BUKCAP;
    for (int i = i0 + threadIdx.x; i < i1; i += 256) {
        const uint2 p = src[i];
        const int row = (b << 8) | ((int)(p.y >> 16) & 255);
        const int pos = atomicAdd(&cursorL[row], 1) + boff[row >> 10];
        ev[pos] = make_uint2(p.x, p.y & 0xFFFFu);
    }
}

// ---------------- K5: SpMM + LeakyReLU — 2 rows/wave, float2 cols -----------
__global__ __launch_bounds__(256) void k_spmm(
    const int* __restrict__ startL, const int* __restrict__ boff,
    const uint2* __restrict__ ev, const float* __restrict__ X,
    float* __restrict__ out)
{
    const int lane = threadIdx.x & 63;
    const int hl   = lane & 31;
    const int sb   = lane & 32;
    const int row  = blockIdx.x * 8 + ((threadIdx.x >> 6) << 1) + (lane >> 5);
    const int s  = startL[row] + boff[row >> 10];
    const int e2 = startL[row + 1] + boff[(row + 1) >> 10];
    float2 acc = make_float2(0.f, 0.f);
    for (int c = s; c < e2; c += 32) {
        const int idx = c + hl;
        uint2 p = make_uint2(0u, 0u);
        if (idx < e2) p = ev[idx];
        const int cnt = min(e2 - c, 32);
        int j = 0;
        for (; j + 3 < cnt; j += 4) {
            const float v0 = __uint_as_float(__shfl((int)p.x, sb + j,     64));
            const int   c0 = __shfl((int)p.y, sb + j,     64) & 0xFFFF;
            const float v1 = __uint_as_float(__shfl((int)p.x, sb + j + 1, 64));
            const int   c1 = __shfl((int)p.y, sb + j + 1, 64) & 0xFFFF;
            const float v2 = __uint_as_float(__shfl((int)p.x, sb + j + 2, 64));
            const int   c2 = __shfl((int)p.y, sb + j + 2, 64) & 0xFFFF;
            const float v3 = __uint_as_float(__shfl((int)p.x, sb + j + 3, 64));
            const int   c3 = __shfl((int)p.y, sb + j + 3, 64) & 0xFFFF;
            const float2 x0 = *(const float2*)(X + c0 * DOUT + hl * 2);
            const float2 x1 = *(const float2*)(X + c1 * DOUT + hl * 2);
            const float2 x2 = *(const float2*)(X + c2 * DOUT + hl * 2);
            const float2 x3 = *(const float2*)(X + c3 * DOUT + hl * 2);
            acc.x = fmaf(v0, x0.x, acc.x); acc.y = fmaf(v0, x0.y, acc.y);
            acc.x = fmaf(v1, x1.x, acc.x); acc.y = fmaf(v1, x1.y, acc.y);
            acc.x = fmaf(v2, x2.x, acc.x); acc.y = fmaf(v2, x2.y, acc.y);
            acc.x = fmaf(v3, x3.x, acc.x); acc.y = fmaf(v3, x3.y, acc.y);
        }
        for (; j < cnt; ++j) {
            const float v = __uint_as_float(__shfl((int)p.x, sb + j, 64));
            const int  cc = __shfl((int)p.y, sb + j, 64) & 0xFFFF;
            const float2 xx = *(const float2*)(X + cc * DOUT + hl * 2);
            acc.x = fmaf(v, xx.x, acc.x);
            acc.y = fmaf(v, xx.y, acc.y);
        }
    }
    float2 r;
    r.x = (acc.x >= 0.f) ? acc.x : 0.01f * acc.x;
    r.y = (acc.y >= 0.f) ? acc.y : 0.01f * acc.y;
    *(float2*)(out + (size_t)row * DOUT + hl * 2) = r;
}

extern "C" void kernel_launch(void* const* d_in, const int* in_sizes, int n_in,
                              void* d_out, int out_size, void* d_ws, size_t ws_size,
                              hipStream_t stream)
{
    const float* H     = (const float*)d_in[0];
    const int*   rows  = (const int*)  d_in[1];
    const int*   cols  = (const int*)  d_in[2];
    const float* vals  = (const float*)d_in[3];
    const float* gamma = (const float*)d_in[4];
    const float* beta  = (const float*)d_in[5];
    const float* mean  = (const float*)d_in[6];
    const float* var   = (const float*)d_in[7];
    const float* W     = (const float*)d_in[8];
    const float* bias  = (const float*)d_in[9];
    float* out = (float*)d_out;

    char* ws = (char*)d_ws;
    float*          X       = (float*)(ws);                    // 12,800,000 B
    int*            cnt     = (int*)  (ws + 12800000);         //    200,000 B
    int*            gcursor = (int*)  (ws + 13000000);         //        784 B
    int*            startL  = (int*)  (ws + 13000800);         //    200,004 B
    int*            cursorL = (int*)  (ws + 13200816);         //    200,000 B
    int*            bsum    = (int*)  (ws + 13400816);         //        196 B
    int*            boff    = (int*)  (ws + 13401024);         //        196 B
    uint2*          mid     = (uint2*)(ws + 13401280);         //  7,225,344 B
    uint2*          ev      = (uint2*)(ws + 20626624);         //  6,400,000 B
    unsigned short* Wt      = (unsigned short*)(ws + 27026624); //    16,384 B
    float*          sc      = (float*)(ws + 27043008);         //        512 B
    float*          sh      = (float*)(ws + 27043520);         //        512 B

    // zero cnt + gcursor in one shot (adjacent)
    hipMemsetAsync(cnt, 0, 200784, stream);

    k_prep<<<32, 256, 0, stream>>>(W, gamma, beta, mean, var, Wt, sc, sh);
    k_x<<<(N_NODES + 63) / 64, 256, 0, stream>>>(H, sc, sh, Wt, bias, X);
    k_passA<<<(E_EDGES + 1023) / 1024, 256, 0, stream>>>(rows, cols, vals, cnt, gcursor, mid);
    k_rscan1<<<49, 256, 0, stream>>>(cnt, startL, cursorL, bsum);
    k_rscan2<<<1, 64, 0, stream>>>(bsum, boff);
    k_scatter2<<<NBUK * 5, 256, 0, stream>>>(gcursor, mid, cursorL, boff, ev);
    k_spmm<<<N_NODES / 8, 256, 0, stream>>>(startL, boff, ev, X, out);
}